// Round 16
// baseline (440.701 us; speedup 1.0000x reference)
//
#include <hip/hip_runtime.h>

// NodeNetwork fused kernel = R15 (198.8us proven: dot2 GEMMs, f16 LDS, nt
// mailbox loads) + nontemporal on the REMAINING streams: feat/hid loads (102MB
// read-once) and out stores (102MB write-once). Same mechanism as R15's win
// (skip L2/L3 line-install on streaming data), applied to the last 20% of traffic.
constexpr int NB = 64;
constexpr int THREADS = 256;
constexpr int X1SU = 66;   // x1 row stride in u32 (128 f16 + 4 pad)
constexpr int H1SU = 50;   // h1 row stride in u32 (96 f16 + 4 pad), aliases x1 region
constexpr int X2SU = 35;   // x2/h2 row stride in u32 (odd -> conflict-free)

// packed-weight layout in d_ws (u32 = 2 f16, pairs along k):
constexpr int W1A_OFF = 0;      // 64 k2-rows x 96 j
constexpr int W1B_OFF = 6144;   // 48 x 64
constexpr int W2A_OFF = 9216;   // 32 x 64
constexpr int W2B_OFF = 11264;  // 32 x 64
constexpr int WTOTAL  = 13312;

typedef __fp16 half2_t __attribute__((ext_vector_type(2)));
typedef float vf4 __attribute__((ext_vector_type(4)));

__device__ __forceinline__ float fast_tanh(float x) {
    // tanh(x) = 1 - 2/(exp(2x)+1); v_exp+v_rcp, abs err ~1e-6, saturates to +-1.
    float e = __expf(2.0f * x);
    return 1.0f - 2.0f * __builtin_amdgcn_rcpf(e + 1.0f);
}

__device__ __forceinline__ unsigned pk16(float a, float b) {
    half2_t h = __builtin_amdgcn_cvt_pkrtz(a, b);
    return __builtin_bit_cast(unsigned, h);
}

__device__ __forceinline__ half2_t uh(unsigned u) {
    return __builtin_bit_cast(half2_t, u);
}

// acc[j] += pa . w0[j] + pb . w1[j]
__device__ __forceinline__ void dot24(half2_t pa, half2_t pb,
                                      const unsigned* __restrict__ w0,
                                      const unsigned* __restrict__ w1,
                                      float* __restrict__ acc) {
    #pragma unroll
    for (int j = 0; j < 24; ++j) acc[j] = __builtin_amdgcn_fdot2(pa, uh(w0[j]), acc[j], false);
    #pragma unroll
    for (int j = 0; j < 24; ++j) acc[j] = __builtin_amdgcn_fdot2(pb, uh(w1[j]), acc[j], false);
}

__device__ __forceinline__ void dot16(half2_t pa, half2_t pb,
                                      const unsigned* __restrict__ w0,
                                      const unsigned* __restrict__ w1,
                                      float* __restrict__ acc) {
    #pragma unroll
    for (int j = 0; j < 16; ++j) acc[j] = __builtin_amdgcn_fdot2(pa, uh(w0[j]), acc[j], false);
    #pragma unroll
    for (int j = 0; j < 16; ++j) acc[j] = __builtin_amdgcn_fdot2(pb, uh(w1[j]), acc[j], false);
}

// ---- pre-kernel: pack f32 weights into f16 pairs (along k) in d_ws ----
__global__ __launch_bounds__(256) void cvt_weights(
    const float* __restrict__ w1a, const float* __restrict__ w1b,
    const float* __restrict__ w2a, const float* __restrict__ w2b,
    unsigned* __restrict__ wp)
{
    int idx = blockIdx.x * 256 + threadIdx.x;    // 0..13311
    const float* src; int cols, rel;
    if (idx < W1B_OFF)      { rel = idx;           src = w1a; cols = 96; }
    else if (idx < W2A_OFF) { rel = idx - W1B_OFF; src = w1b; cols = 64; }
    else if (idx < W2B_OFF) { rel = idx - W2A_OFF; src = w2a; cols = 64; }
    else                    { rel = idx - W2B_OFF; src = w2b; cols = 64; }
    int k2 = rel / cols, j = rel - k2 * cols;
    wp[idx] = pk16(src[(2 * k2) * cols + j], src[(2 * k2 + 1) * cols + j]);
}

__global__ __launch_bounds__(THREADS) void node_net_kernel(
    const float* __restrict__ feat, const float* __restrict__ hid,
    const float* __restrict__ mail,
    const float* __restrict__ b1a, const float* __restrict__ b1b,
    const float* __restrict__ b2a, const float* __restrict__ b2b,
    const unsigned* __restrict__ wp,
    float* __restrict__ out)
{
    __shared__ unsigned ldsA[NB * X1SU];   // x1 f16, later h1 f16
    __shared__ unsigned ldsB[NB * X2SU];   // x2 f16, later h2 f16
    __shared__ float    ldsS[NB * 4];      // per-sub partial sumsq

    const int t  = threadIdx.x;
    const int n0 = blockIdx.x * NB;
    const int c4 = t & 15;             // float4 column 0..15
    const int nb = t >> 4;             // node base 0..15; owns nodes nb+16c (mailbox/staging)

    // mailbox chain bases: [N][16][64] -> node stride 256 f4, depth stride 16 f4
    const vf4* mb0 = reinterpret_cast<const vf4*>(mail) + (size_t)(n0 + nb) * 256 + c4;

    // ---------- Phase 1: stage x1 = [feat|hid] as f16 (nt loads) ----------
    #pragma unroll
    for (int i = 0; i < 4; ++i) {
        int n = nb + 16 * i;
        vf4 f = __builtin_nontemporal_load(reinterpret_cast<const vf4*>(feat) + (size_t)(n0 + n) * 16 + c4);
        vf4 g = __builtin_nontemporal_load(reinterpret_cast<const vf4*>(hid ) + (size_t)(n0 + n) * 16 + c4);
        unsigned* dst = &ldsA[n * X1SU];
        *reinterpret_cast<uint2*>(dst + c4 * 2)      = make_uint2(pk16(f.x, f.y), pk16(f.z, f.w));
        *reinterpret_cast<uint2*>(dst + 32 + c4 * 2) = make_uint2(pk16(g.x, g.y), pk16(g.z, g.w));
    }
    __syncthreads();                       // B1: x1 visible

    const int node = t & 63;
    const int sub  = __builtin_amdgcn_readfirstlane(t >> 6);  // wave id 0..3, uniform

    // ---------- Phase 2: h1 = relu(x1 @ w1a + b1a), j-slice of 24,
    //            with mailbox streaming (nontemporal) pinned under dot2 stream ----------
    float acc1[24];
    {
        const float* b = b1a + sub * 24;
        #pragma unroll
        for (int j = 0; j < 24; ++j) acc1[j] = b[j];
    }
    {
        const unsigned* xr = &ldsA[node * X1SU];
        const unsigned* w1aP = wp + W1A_OFF + sub * 24;
        #pragma unroll 1
        for (int c = 0; c < 4; ++c) {                      // chain c: node nb+16c
            const vf4* chain = mb0 + (size_t)c * 4096;     // 16 nodes * 256 f4
            vf4 m;
            #pragma unroll
            for (int half = 0; half < 2; ++half) {         // depths [8*half, 8*half+8)
                vf4 cur[8];
                #pragma unroll
                for (int d = 0; d < 8; ++d)
                    cur[d] = __builtin_nontemporal_load(chain + (half * 8 + d) * 16);
                __builtin_amdgcn_sched_barrier(0);         // pin: loads issued above
                // 4 k4-iterations (192 dot2) run while the 8 loads are in flight
                #pragma unroll
                for (int kk = 0; kk < 4; ++kk) {
                    int k4 = (c * 2 + half) * 4 + kk;
                    uint2 xu = *reinterpret_cast<const uint2*>(xr + 2 * k4);
                    dot24(uh(xu.x), uh(xu.y),
                          w1aP + (2 * k4) * 96, w1aP + (2 * k4 + 1) * 96, acc1);
                }
                __builtin_amdgcn_sched_barrier(0);         // pin: consume below
                vf4 s = ((cur[0] + cur[1]) + (cur[2] + cur[3]))
                      + ((cur[4] + cur[5]) + (cur[6] + cur[7]));
                if (half == 0) m = s; else m += s;         // static (half unrolled)
            }
            // x2 row (f16 pairs) for node nb+16c; ldsB untouched until after B2
            *reinterpret_cast<uint2*>(&ldsB[(nb + 16 * c) * X2SU + c4 * 2]) =
                make_uint2(pk16(m.x, m.y), pk16(m.z, m.w));
        }
    }
    __syncthreads();                     // B2: all x1 reads done; reuse ldsA for h1
    {
        unsigned* hv = &ldsA[node * H1SU + sub * 12];
        #pragma unroll
        for (int p = 0; p < 12; ++p)
            hv[p] = pk16(fmaxf(acc1[2*p], 0.f), fmaxf(acc1[2*p + 1], 0.f));
    }
    __syncthreads();                     // B3: h1 visible

    // ---------- Phase 3: r1 = tanh(h1 @ w1b + b1b), j-slice of 16 ----------
    float r1v[16];
    {
        float acc[16];
        const float* b = b1b + sub * 16;
        #pragma unroll
        for (int j = 0; j < 16; ++j) acc[j] = b[j];
        const unsigned* hb = &ldsA[node * H1SU];
        const unsigned* w1bP = wp + W1B_OFF + sub * 16;
        #pragma unroll 2
        for (int k4 = 0; k4 < 24; ++k4) {
            uint2 hu2 = *reinterpret_cast<const uint2*>(hb + 2 * k4);
            dot16(uh(hu2.x), uh(hu2.y),
                  w1bP + (2 * k4) * 64, w1bP + (2 * k4 + 1) * 64, acc);
        }
        #pragma unroll
        for (int j = 0; j < 16; ++j) r1v[j] = fast_tanh(acc[j]);
    }

    // ---------- Phase 4: h2 = relu(x2 @ w2a + b2a), j-slice of 16 ----------
    float h2v[16];
    {
        float acc[16];
        const float* b = b2a + sub * 16;
        #pragma unroll
        for (int j = 0; j < 16; ++j) acc[j] = b[j];
        const unsigned* xb = &ldsB[node * X2SU];
        const unsigned* w2aP = wp + W2A_OFF + sub * 16;
        #pragma unroll 2
        for (int k4 = 0; k4 < 16; ++k4) {
            uint2 xu = *reinterpret_cast<const uint2*>(xb + 2 * k4);
            dot16(uh(xu.x), uh(xu.y),
                  w2aP + (2 * k4) * 64, w2aP + (2 * k4 + 1) * 64, acc);
        }
        #pragma unroll
        for (int j = 0; j < 16; ++j) h2v[j] = fmaxf(acc[j], 0.f);
    }
    __syncthreads();                     // B4: x2 reads done; reuse ldsB for h2
    {
        unsigned* hrow = &ldsB[node * X2SU + sub * 8];
        #pragma unroll
        for (int p = 0; p < 8; ++p)
            hrow[p] = pk16(h2v[2*p], h2v[2*p + 1]);
    }
    __syncthreads();                     // B5: h2 visible

    // ---------- Phase 5: r2 = tanh(h2 @ w2b + b2b), j-slice of 16 ----------
    float r2v[16];
    {
        float acc[16];
        const float* b = b2b + sub * 16;
        #pragma unroll
        for (int j = 0; j < 16; ++j) acc[j] = b[j];
        const unsigned* hb2 = &ldsB[node * X2SU];
        const unsigned* w2bP = wp + W2B_OFF + sub * 16;
        #pragma unroll 2
        for (int k4 = 0; k4 < 16; ++k4) {
            uint2 xu = *reinterpret_cast<const uint2*>(hb2 + 2 * k4);
            dot16(uh(xu.x), uh(xu.y),
                  w2bP + (2 * k4) * 64, w2bP + (2 * k4 + 1) * 64, acc);
        }
        #pragma unroll
        for (int j = 0; j < 16; ++j) r2v[j] = fast_tanh(acc[j]);
    }

    // ---------- Phase 6: row L2 norm + write (nt stores) ----------
    float s = 0.f;
    #pragma unroll
    for (int j = 0; j < 16; ++j) s = fmaf(r1v[j], r1v[j], s);
    #pragma unroll
    for (int j = 0; j < 16; ++j) s = fmaf(r2v[j], r2v[j], s);
    ldsS[node * 4 + sub] = s;
    __syncthreads();                     // B6
    float4 sv = reinterpret_cast<const float4*>(ldsS)[node];
    float rn = rsqrtf(sv.x + sv.y + sv.z + sv.w);

    float* orow = out + (size_t)(n0 + node) * 128;
    vf4* o1 = reinterpret_cast<vf4*>(orow + sub * 16);
    vf4* o2 = reinterpret_cast<vf4*>(orow + 64 + sub * 16);
    #pragma unroll
    for (int j4 = 0; j4 < 4; ++j4) {
        vf4 a = {r1v[j4*4+0]*rn, r1v[j4*4+1]*rn, r1v[j4*4+2]*rn, r1v[j4*4+3]*rn};
        vf4 b = {r2v[j4*4+0]*rn, r2v[j4*4+1]*rn, r2v[j4*4+2]*rn, r2v[j4*4+3]*rn};
        __builtin_nontemporal_store(a, o1 + j4);
        __builtin_nontemporal_store(b, o2 + j4);
    }
}

extern "C" void kernel_launch(void* const* d_in, const int* in_sizes, int n_in,
                              void* d_out, int out_size, void* d_ws, size_t ws_size,
                              hipStream_t stream) {
    const float* feat = (const float*)d_in[0];
    const float* hid  = (const float*)d_in[1];
    const float* mail = (const float*)d_in[2];
    const float* w1a  = (const float*)d_in[3];
    const float* b1a  = (const float*)d_in[4];
    const float* w1b  = (const float*)d_in[5];
    const float* b1b  = (const float*)d_in[6];
    const float* w2a  = (const float*)d_in[7];
    const float* b2a  = (const float*)d_in[8];
    const float* w2b  = (const float*)d_in[9];
    const float* b2b  = (const float*)d_in[10];
    float* out = (float*)d_out;
    unsigned* wp = (unsigned*)d_ws;          // 13312 u32 = 53KB packed f16 weights

    const int N = in_sizes[0] / 64;          // 200000
    const int blocks = N / NB;               // 3125

    cvt_weights<<<WTOTAL / 256, 256, 0, stream>>>(w1a, w1b, w2a, w2b, wp);
    node_net_kernel<<<blocks, THREADS, 0, stream>>>(
        feat, hid, mail, b1a, b1b, b2a, b2b, wp, out);
}

// Round 17
// 203.639 us; speedup vs baseline: 2.1641x; 2.1641x over previous
//
#include <hip/hip_runtime.h>

// NodeNetwork fused kernel = R15 (198.8us proven: dot2 GEMMs, f16 LDS, nt
// mailbox loads) + nt on feat/hid LOADS only. R16 lesson: nt STORES defeat
// write-combining on gfx950 (198->441us) — stores stay on the normal path.
constexpr int NB = 64;
constexpr int THREADS = 256;
constexpr int X1SU = 66;   // x1 row stride in u32 (128 f16 + 4 pad)
constexpr int H1SU = 50;   // h1 row stride in u32 (96 f16 + 4 pad), aliases x1 region
constexpr int X2SU = 35;   // x2/h2 row stride in u32 (odd -> conflict-free)

// packed-weight layout in d_ws (u32 = 2 f16, pairs along k):
constexpr int W1A_OFF = 0;      // 64 k2-rows x 96 j
constexpr int W1B_OFF = 6144;   // 48 x 64
constexpr int W2A_OFF = 9216;   // 32 x 64
constexpr int W2B_OFF = 11264;  // 32 x 64
constexpr int WTOTAL  = 13312;

typedef __fp16 half2_t __attribute__((ext_vector_type(2)));
typedef float vf4 __attribute__((ext_vector_type(4)));

__device__ __forceinline__ float fast_tanh(float x) {
    // tanh(x) = 1 - 2/(exp(2x)+1); v_exp+v_rcp, abs err ~1e-6, saturates to +-1.
    float e = __expf(2.0f * x);
    return 1.0f - 2.0f * __builtin_amdgcn_rcpf(e + 1.0f);
}

__device__ __forceinline__ unsigned pk16(float a, float b) {
    half2_t h = __builtin_amdgcn_cvt_pkrtz(a, b);
    return __builtin_bit_cast(unsigned, h);
}

__device__ __forceinline__ half2_t uh(unsigned u) {
    return __builtin_bit_cast(half2_t, u);
}

// acc[j] += pa . w0[j] + pb . w1[j]
__device__ __forceinline__ void dot24(half2_t pa, half2_t pb,
                                      const unsigned* __restrict__ w0,
                                      const unsigned* __restrict__ w1,
                                      float* __restrict__ acc) {
    #pragma unroll
    for (int j = 0; j < 24; ++j) acc[j] = __builtin_amdgcn_fdot2(pa, uh(w0[j]), acc[j], false);
    #pragma unroll
    for (int j = 0; j < 24; ++j) acc[j] = __builtin_amdgcn_fdot2(pb, uh(w1[j]), acc[j], false);
}

__device__ __forceinline__ void dot16(half2_t pa, half2_t pb,
                                      const unsigned* __restrict__ w0,
                                      const unsigned* __restrict__ w1,
                                      float* __restrict__ acc) {
    #pragma unroll
    for (int j = 0; j < 16; ++j) acc[j] = __builtin_amdgcn_fdot2(pa, uh(w0[j]), acc[j], false);
    #pragma unroll
    for (int j = 0; j < 16; ++j) acc[j] = __builtin_amdgcn_fdot2(pb, uh(w1[j]), acc[j], false);
}

// ---- pre-kernel: pack f32 weights into f16 pairs (along k) in d_ws ----
__global__ __launch_bounds__(256) void cvt_weights(
    const float* __restrict__ w1a, const float* __restrict__ w1b,
    const float* __restrict__ w2a, const float* __restrict__ w2b,
    unsigned* __restrict__ wp)
{
    int idx = blockIdx.x * 256 + threadIdx.x;    // 0..13311
    const float* src; int cols, rel;
    if (idx < W1B_OFF)      { rel = idx;           src = w1a; cols = 96; }
    else if (idx < W2A_OFF) { rel = idx - W1B_OFF; src = w1b; cols = 64; }
    else if (idx < W2B_OFF) { rel = idx - W2A_OFF; src = w2a; cols = 64; }
    else                    { rel = idx - W2B_OFF; src = w2b; cols = 64; }
    int k2 = rel / cols, j = rel - k2 * cols;
    wp[idx] = pk16(src[(2 * k2) * cols + j], src[(2 * k2 + 1) * cols + j]);
}

__global__ __launch_bounds__(THREADS) void node_net_kernel(
    const float* __restrict__ feat, const float* __restrict__ hid,
    const float* __restrict__ mail,
    const float* __restrict__ b1a, const float* __restrict__ b1b,
    const float* __restrict__ b2a, const float* __restrict__ b2b,
    const unsigned* __restrict__ wp,
    float* __restrict__ out)
{
    __shared__ unsigned ldsA[NB * X1SU];   // x1 f16, later h1 f16
    __shared__ unsigned ldsB[NB * X2SU];   // x2 f16, later h2 f16
    __shared__ float    ldsS[NB * 4];      // per-sub partial sumsq

    const int t  = threadIdx.x;
    const int n0 = blockIdx.x * NB;
    const int c4 = t & 15;             // float4 column 0..15
    const int nb = t >> 4;             // node base 0..15; owns nodes nb+16c (mailbox/staging)

    // mailbox chain bases: [N][16][64] -> node stride 256 f4, depth stride 16 f4
    const vf4* mb0 = reinterpret_cast<const vf4*>(mail) + (size_t)(n0 + nb) * 256 + c4;

    // ---------- Phase 1: stage x1 = [feat|hid] as f16 (nt loads) ----------
    #pragma unroll
    for (int i = 0; i < 4; ++i) {
        int n = nb + 16 * i;
        vf4 f = __builtin_nontemporal_load(reinterpret_cast<const vf4*>(feat) + (size_t)(n0 + n) * 16 + c4);
        vf4 g = __builtin_nontemporal_load(reinterpret_cast<const vf4*>(hid ) + (size_t)(n0 + n) * 16 + c4);
        unsigned* dst = &ldsA[n * X1SU];
        *reinterpret_cast<uint2*>(dst + c4 * 2)      = make_uint2(pk16(f.x, f.y), pk16(f.z, f.w));
        *reinterpret_cast<uint2*>(dst + 32 + c4 * 2) = make_uint2(pk16(g.x, g.y), pk16(g.z, g.w));
    }
    __syncthreads();                       // B1: x1 visible

    const int node = t & 63;
    const int sub  = __builtin_amdgcn_readfirstlane(t >> 6);  // wave id 0..3, uniform

    // ---------- Phase 2: h1 = relu(x1 @ w1a + b1a), j-slice of 24,
    //            with mailbox streaming (nontemporal) pinned under dot2 stream ----------
    float acc1[24];
    {
        const float* b = b1a + sub * 24;
        #pragma unroll
        for (int j = 0; j < 24; ++j) acc1[j] = b[j];
    }
    {
        const unsigned* xr = &ldsA[node * X1SU];
        const unsigned* w1aP = wp + W1A_OFF + sub * 24;
        #pragma unroll 1
        for (int c = 0; c < 4; ++c) {                      // chain c: node nb+16c
            const vf4* chain = mb0 + (size_t)c * 4096;     // 16 nodes * 256 f4
            vf4 m;
            #pragma unroll
            for (int half = 0; half < 2; ++half) {         // depths [8*half, 8*half+8)
                vf4 cur[8];
                #pragma unroll
                for (int d = 0; d < 8; ++d)
                    cur[d] = __builtin_nontemporal_load(chain + (half * 8 + d) * 16);
                __builtin_amdgcn_sched_barrier(0);         // pin: loads issued above
                // 4 k4-iterations (192 dot2) run while the 8 loads are in flight
                #pragma unroll
                for (int kk = 0; kk < 4; ++kk) {
                    int k4 = (c * 2 + half) * 4 + kk;
                    uint2 xu = *reinterpret_cast<const uint2*>(xr + 2 * k4);
                    dot24(uh(xu.x), uh(xu.y),
                          w1aP + (2 * k4) * 96, w1aP + (2 * k4 + 1) * 96, acc1);
                }
                __builtin_amdgcn_sched_barrier(0);         // pin: consume below
                vf4 s = ((cur[0] + cur[1]) + (cur[2] + cur[3]))
                      + ((cur[4] + cur[5]) + (cur[6] + cur[7]));
                if (half == 0) m = s; else m += s;         // static (half unrolled)
            }
            // x2 row (f16 pairs) for node nb+16c; ldsB untouched until after B2
            *reinterpret_cast<uint2*>(&ldsB[(nb + 16 * c) * X2SU + c4 * 2]) =
                make_uint2(pk16(m.x, m.y), pk16(m.z, m.w));
        }
    }
    __syncthreads();                     // B2: all x1 reads done; reuse ldsA for h1
    {
        unsigned* hv = &ldsA[node * H1SU + sub * 12];
        #pragma unroll
        for (int p = 0; p < 12; ++p)
            hv[p] = pk16(fmaxf(acc1[2*p], 0.f), fmaxf(acc1[2*p + 1], 0.f));
    }
    __syncthreads();                     // B3: h1 visible

    // ---------- Phase 3: r1 = tanh(h1 @ w1b + b1b), j-slice of 16 ----------
    float r1v[16];
    {
        float acc[16];
        const float* b = b1b + sub * 16;
        #pragma unroll
        for (int j = 0; j < 16; ++j) acc[j] = b[j];
        const unsigned* hb = &ldsA[node * H1SU];
        const unsigned* w1bP = wp + W1B_OFF + sub * 16;
        #pragma unroll 2
        for (int k4 = 0; k4 < 24; ++k4) {
            uint2 hu2 = *reinterpret_cast<const uint2*>(hb + 2 * k4);
            dot16(uh(hu2.x), uh(hu2.y),
                  w1bP + (2 * k4) * 64, w1bP + (2 * k4 + 1) * 64, acc);
        }
        #pragma unroll
        for (int j = 0; j < 16; ++j) r1v[j] = fast_tanh(acc[j]);
    }

    // ---------- Phase 4: h2 = relu(x2 @ w2a + b2a), j-slice of 16 ----------
    float h2v[16];
    {
        float acc[16];
        const float* b = b2a + sub * 16;
        #pragma unroll
        for (int j = 0; j < 16; ++j) acc[j] = b[j];
        const unsigned* xb = &ldsB[node * X2SU];
        const unsigned* w2aP = wp + W2A_OFF + sub * 16;
        #pragma unroll 2
        for (int k4 = 0; k4 < 16; ++k4) {
            uint2 xu = *reinterpret_cast<const uint2*>(xb + 2 * k4);
            dot16(uh(xu.x), uh(xu.y),
                  w2aP + (2 * k4) * 64, w2aP + (2 * k4 + 1) * 64, acc);
        }
        #pragma unroll
        for (int j = 0; j < 16; ++j) h2v[j] = fmaxf(acc[j], 0.f);
    }
    __syncthreads();                     // B4: x2 reads done; reuse ldsB for h2
    {
        unsigned* hrow = &ldsB[node * X2SU + sub * 8];
        #pragma unroll
        for (int p = 0; p < 8; ++p)
            hrow[p] = pk16(h2v[2*p], h2v[2*p + 1]);
    }
    __syncthreads();                     // B5: h2 visible

    // ---------- Phase 5: r2 = tanh(h2 @ w2b + b2b), j-slice of 16 ----------
    float r2v[16];
    {
        float acc[16];
        const float* b = b2b + sub * 16;
        #pragma unroll
        for (int j = 0; j < 16; ++j) acc[j] = b[j];
        const unsigned* hb2 = &ldsB[node * X2SU];
        const unsigned* w2bP = wp + W2B_OFF + sub * 16;
        #pragma unroll 2
        for (int k4 = 0; k4 < 16; ++k4) {
            uint2 xu = *reinterpret_cast<const uint2*>(hb2 + 2 * k4);
            dot16(uh(xu.x), uh(xu.y),
                  w2bP + (2 * k4) * 64, w2bP + (2 * k4 + 1) * 64, acc);
        }
        #pragma unroll
        for (int j = 0; j < 16; ++j) r2v[j] = fast_tanh(acc[j]);
    }

    // ---------- Phase 6: row L2 norm + write (NORMAL stores — R16 lesson) ----------
    float s = 0.f;
    #pragma unroll
    for (int j = 0; j < 16; ++j) s = fmaf(r1v[j], r1v[j], s);
    #pragma unroll
    for (int j = 0; j < 16; ++j) s = fmaf(r2v[j], r2v[j], s);
    ldsS[node * 4 + sub] = s;
    __syncthreads();                     // B6
    float4 sv = reinterpret_cast<const float4*>(ldsS)[node];
    float rn = rsqrtf(sv.x + sv.y + sv.z + sv.w);

    float* orow = out + (size_t)(n0 + node) * 128;
    float4* o1 = reinterpret_cast<float4*>(orow + sub * 16);
    float4* o2 = reinterpret_cast<float4*>(orow + 64 + sub * 16);
    #pragma unroll
    for (int j4 = 0; j4 < 4; ++j4) {
        o1[j4] = make_float4(r1v[j4*4+0]*rn, r1v[j4*4+1]*rn, r1v[j4*4+2]*rn, r1v[j4*4+3]*rn);
        o2[j4] = make_float4(r2v[j4*4+0]*rn, r2v[j4*4+1]*rn, r2v[j4*4+2]*rn, r2v[j4*4+3]*rn);
    }
}

extern "C" void kernel_launch(void* const* d_in, const int* in_sizes, int n_in,
                              void* d_out, int out_size, void* d_ws, size_t ws_size,
                              hipStream_t stream) {
    const float* feat = (const float*)d_in[0];
    const float* hid  = (const float*)d_in[1];
    const float* mail = (const float*)d_in[2];
    const float* w1a  = (const float*)d_in[3];
    const float* b1a  = (const float*)d_in[4];
    const float* w1b  = (const float*)d_in[5];
    const float* b1b  = (const float*)d_in[6];
    const float* w2a  = (const float*)d_in[7];
    const float* b2a  = (const float*)d_in[8];
    const float* w2b  = (const float*)d_in[9];
    const float* b2b  = (const float*)d_in[10];
    float* out = (float*)d_out;
    unsigned* wp = (unsigned*)d_ws;          // 13312 u32 = 53KB packed f16 weights

    const int N = in_sizes[0] / 64;          // 200000
    const int blocks = N / NB;               // 3125

    cvt_weights<<<WTOTAL / 256, 256, 0, stream>>>(w1a, w1b, w2a, w2b, wp);
    node_net_kernel<<<blocks, THREADS, 0, stream>>>(
        feat, hid, mail, b1a, b1b, b2a, b2b, wp, out);
}

// Round 19
// 197.715 us; speedup vs baseline: 2.2290x; 1.0300x over previous
//
#include <hip/hip_runtime.h>

// NodeNetwork fused kernel = R15 (198.8us proven: dot2 GEMMs, f16 LDS, nt
// mailbox loads, NORMAL feat/hid loads + stores) + tail-fill: chain 3's
// depths 8-15 stream under P3's dot16 phase (8-deep register batch, partial
// sum carried in one vf4 across barriers). Tests whether the P3 HBM-idle
// window is real remaining cost. R16/R17 lessons: nt ONLY on mailbox.
constexpr int NB = 64;
constexpr int THREADS = 256;
constexpr int X1SU = 66;   // x1 row stride in u32 (128 f16 + 4 pad)
constexpr int H1SU = 50;   // h1 row stride in u32 (96 f16 + 4 pad), aliases x1 region
constexpr int X2SU = 35;   // x2/h2 row stride in u32 (odd -> conflict-free)

// packed-weight layout in d_ws (u32 = 2 f16, pairs along k):
constexpr int W1A_OFF = 0;      // 64 k2-rows x 96 j
constexpr int W1B_OFF = 6144;   // 48 x 64
constexpr int W2A_OFF = 9216;   // 32 x 64
constexpr int W2B_OFF = 11264;  // 32 x 64
constexpr int WTOTAL  = 13312;

typedef __fp16 half2_t __attribute__((ext_vector_type(2)));
typedef float vf4 __attribute__((ext_vector_type(4)));

__device__ __forceinline__ float fast_tanh(float x) {
    // tanh(x) = 1 - 2/(exp(2x)+1); v_exp+v_rcp, abs err ~1e-6, saturates to +-1.
    float e = __expf(2.0f * x);
    return 1.0f - 2.0f * __builtin_amdgcn_rcpf(e + 1.0f);
}

__device__ __forceinline__ unsigned pk16(float a, float b) {
    half2_t h = __builtin_amdgcn_cvt_pkrtz(a, b);
    return __builtin_bit_cast(unsigned, h);
}

__device__ __forceinline__ half2_t uh(unsigned u) {
    return __builtin_bit_cast(half2_t, u);
}

// acc[j] += pa . w0[j] + pb . w1[j]
__device__ __forceinline__ void dot24(half2_t pa, half2_t pb,
                                      const unsigned* __restrict__ w0,
                                      const unsigned* __restrict__ w1,
                                      float* __restrict__ acc) {
    #pragma unroll
    for (int j = 0; j < 24; ++j) acc[j] = __builtin_amdgcn_fdot2(pa, uh(w0[j]), acc[j], false);
    #pragma unroll
    for (int j = 0; j < 24; ++j) acc[j] = __builtin_amdgcn_fdot2(pb, uh(w1[j]), acc[j], false);
}

__device__ __forceinline__ void dot16(half2_t pa, half2_t pb,
                                      const unsigned* __restrict__ w0,
                                      const unsigned* __restrict__ w1,
                                      float* __restrict__ acc) {
    #pragma unroll
    for (int j = 0; j < 16; ++j) acc[j] = __builtin_amdgcn_fdot2(pa, uh(w0[j]), acc[j], false);
    #pragma unroll
    for (int j = 0; j < 16; ++j) acc[j] = __builtin_amdgcn_fdot2(pb, uh(w1[j]), acc[j], false);
}

// ---- pre-kernel: pack f32 weights into f16 pairs (along k) in d_ws ----
__global__ __launch_bounds__(256) void cvt_weights(
    const float* __restrict__ w1a, const float* __restrict__ w1b,
    const float* __restrict__ w2a, const float* __restrict__ w2b,
    unsigned* __restrict__ wp)
{
    int idx = blockIdx.x * 256 + threadIdx.x;    // 0..13311
    const float* src; int cols, rel;
    if (idx < W1B_OFF)      { rel = idx;           src = w1a; cols = 96; }
    else if (idx < W2A_OFF) { rel = idx - W1B_OFF; src = w1b; cols = 64; }
    else if (idx < W2B_OFF) { rel = idx - W2A_OFF; src = w2a; cols = 64; }
    else                    { rel = idx - W2B_OFF; src = w2b; cols = 64; }
    int k2 = rel / cols, j = rel - k2 * cols;
    wp[idx] = pk16(src[(2 * k2) * cols + j], src[(2 * k2 + 1) * cols + j]);
}

__global__ __launch_bounds__(THREADS) void node_net_kernel(
    const float* __restrict__ feat, const float* __restrict__ hid,
    const float* __restrict__ mail,
    const float* __restrict__ b1a, const float* __restrict__ b1b,
    const float* __restrict__ b2a, const float* __restrict__ b2b,
    const unsigned* __restrict__ wp,
    float* __restrict__ out)
{
    __shared__ unsigned ldsA[NB * X1SU];   // x1 f16, later h1 f16
    __shared__ unsigned ldsB[NB * X2SU];   // x2 f16, later h2 f16
    __shared__ float    ldsS[NB * 4];      // per-sub partial sumsq

    const int t  = threadIdx.x;
    const int n0 = blockIdx.x * NB;
    const int c4 = t & 15;             // float4 column 0..15
    const int nb = t >> 4;             // node base 0..15; owns nodes nb+16c (mailbox/staging)

    // mailbox chain bases: [N][16][64] -> node stride 256 f4, depth stride 16 f4
    const vf4* mb0 = reinterpret_cast<const vf4*>(mail) + (size_t)(n0 + nb) * 256 + c4;

    // ---------- Phase 1: stage x1 = [feat|hid] as f16 (normal loads) ----------
    #pragma unroll
    for (int i = 0; i < 4; ++i) {
        int n = nb + 16 * i;
        float4 f = reinterpret_cast<const float4*>(feat)[(size_t)(n0 + n) * 16 + c4];
        float4 g = reinterpret_cast<const float4*>(hid )[(size_t)(n0 + n) * 16 + c4];
        unsigned* dst = &ldsA[n * X1SU];
        *reinterpret_cast<uint2*>(dst + c4 * 2)      = make_uint2(pk16(f.x, f.y), pk16(f.z, f.w));
        *reinterpret_cast<uint2*>(dst + 32 + c4 * 2) = make_uint2(pk16(g.x, g.y), pk16(g.z, g.w));
    }
    __syncthreads();                       // B1: x1 visible

    const int node = t & 63;
    const int sub  = __builtin_amdgcn_readfirstlane(t >> 6);  // wave id 0..3, uniform

    // ---------- Phase 2: h1 = relu(x1 @ w1a + b1a), j-slice of 24,
    //            streaming chains 0-2 fully + chain 3 depths 0-7 (nt, pinned) ----------
    float acc1[24];
    {
        const float* b = b1a + sub * 24;
        #pragma unroll
        for (int j = 0; j < 24; ++j) acc1[j] = b[j];
    }
    vf4 m3;                                 // chain-3 partial (d0-7), completed in P3
    {
        const unsigned* xr = &ldsA[node * X1SU];
        const unsigned* w1aP = wp + W1A_OFF + sub * 24;
        #pragma unroll 1
        for (int c = 0; c < 3; ++c) {                      // chains 0-2: full 16 depths
            const vf4* chain = mb0 + (size_t)c * 4096;     // 16 nodes * 256 f4
            vf4 m;
            #pragma unroll
            for (int half = 0; half < 2; ++half) {         // depths [8*half, 8*half+8)
                vf4 cur[8];
                #pragma unroll
                for (int d = 0; d < 8; ++d)
                    cur[d] = __builtin_nontemporal_load(chain + (half * 8 + d) * 16);
                __builtin_amdgcn_sched_barrier(0);         // pin: loads issued above
                #pragma unroll
                for (int kk = 0; kk < 4; ++kk) {
                    int k4 = (c * 2 + half) * 4 + kk;      // k4 0..23
                    uint2 xu = *reinterpret_cast<const uint2*>(xr + 2 * k4);
                    dot24(uh(xu.x), uh(xu.y),
                          w1aP + (2 * k4) * 96, w1aP + (2 * k4 + 1) * 96, acc1);
                }
                __builtin_amdgcn_sched_barrier(0);         // pin: consume below
                vf4 s = ((cur[0] + cur[1]) + (cur[2] + cur[3]))
                      + ((cur[4] + cur[5]) + (cur[6] + cur[7]));
                if (half == 0) m = s; else m += s;         // static (half unrolled)
            }
            *reinterpret_cast<uint2*>(&ldsB[(nb + 16 * c) * X2SU + c4 * 2]) =
                make_uint2(pk16(m.x, m.y), pk16(m.z, m.w));
        }
        {   // chain 3: depths 0-7 under k4 24..31 (one 8-load batch)
            const vf4* chain = mb0 + (size_t)3 * 4096;
            vf4 cur[8];
            #pragma unroll
            for (int d = 0; d < 8; ++d)
                cur[d] = __builtin_nontemporal_load(chain + d * 16);
            __builtin_amdgcn_sched_barrier(0);
            #pragma unroll
            for (int kk = 0; kk < 8; ++kk) {
                int k4 = 24 + kk;
                uint2 xu = *reinterpret_cast<const uint2*>(xr + 2 * k4);
                dot24(uh(xu.x), uh(xu.y),
                      w1aP + (2 * k4) * 96, w1aP + (2 * k4 + 1) * 96, acc1);
            }
            __builtin_amdgcn_sched_barrier(0);
            m3 = ((cur[0] + cur[1]) + (cur[2] + cur[3]))
               + ((cur[4] + cur[5]) + (cur[6] + cur[7]));
        }
    }
    __syncthreads();                     // B2: all x1 reads done; reuse ldsA for h1
    {
        unsigned* hv = &ldsA[node * H1SU + sub * 12];
        #pragma unroll
        for (int p = 0; p < 12; ++p)
            hv[p] = pk16(fmaxf(acc1[2*p], 0.f), fmaxf(acc1[2*p + 1], 0.f));
    }
    __syncthreads();                     // B3: h1 visible

    // ---------- Phase 3: r1 = tanh(h1 @ w1b + b1b), j-slice of 16,
    //            streaming chain 3 depths 8-15 under the dot16 phase ----------
    float r1v[16];
    {
        float acc[16];
        const float* b = b1b + sub * 16;
        #pragma unroll
        for (int j = 0; j < 16; ++j) acc[j] = b[j];
        const unsigned* hb = &ldsA[node * H1SU];
        const unsigned* w1bP = wp + W1B_OFF + sub * 16;
        const vf4* chain3 = mb0 + (size_t)3 * 4096;
        vf4 cur[8];
        #pragma unroll
        for (int d = 0; d < 8; ++d)
            cur[d] = __builtin_nontemporal_load(chain3 + (8 + d) * 16);
        __builtin_amdgcn_sched_barrier(0);               // pin: loads issued above
        #pragma unroll 2
        for (int k4 = 0; k4 < 24; ++k4) {
            uint2 hu2 = *reinterpret_cast<const uint2*>(hb + 2 * k4);
            dot16(uh(hu2.x), uh(hu2.y),
                  w1bP + (2 * k4) * 64, w1bP + (2 * k4 + 1) * 64, acc);
        }
        __builtin_amdgcn_sched_barrier(0);               // pin: consume below
        m3 += ((cur[0] + cur[1]) + (cur[2] + cur[3]))
            + ((cur[4] + cur[5]) + (cur[6] + cur[7]));
        *reinterpret_cast<uint2*>(&ldsB[(nb + 48) * X2SU + c4 * 2]) =
            make_uint2(pk16(m3.x, m3.y), pk16(m3.z, m3.w));
        #pragma unroll
        for (int j = 0; j < 16; ++j) r1v[j] = fast_tanh(acc[j]);
    }
    __syncthreads();                     // B3.5: chain-3 x2 rows visible for P4

    // ---------- Phase 4: h2 = relu(x2 @ w2a + b2a), j-slice of 16 ----------
    float h2v[16];
    {
        float acc[16];
        const float* b = b2a + sub * 16;
        #pragma unroll
        for (int j = 0; j < 16; ++j) acc[j] = b[j];
        const unsigned* xb = &ldsB[node * X2SU];
        const unsigned* w2aP = wp + W2A_OFF + sub * 16;
        #pragma unroll 2
        for (int k4 = 0; k4 < 16; ++k4) {
            uint2 xu = *reinterpret_cast<const uint2*>(xb + 2 * k4);
            dot16(uh(xu.x), uh(xu.y),
                  w2aP + (2 * k4) * 64, w2aP + (2 * k4 + 1) * 64, acc);
        }
        #pragma unroll
        for (int j = 0; j < 16; ++j) h2v[j] = fmaxf(acc[j], 0.f);
    }
    __syncthreads();                     // B4: x2 reads done; reuse ldsB for h2
    {
        unsigned* hrow = &ldsB[node * X2SU + sub * 8];
        #pragma unroll
        for (int p = 0; p < 8; ++p)
            hrow[p] = pk16(h2v[2*p], h2v[2*p + 1]);
    }
    __syncthreads();                     // B5: h2 visible

    // ---------- Phase 5: r2 = tanh(h2 @ w2b + b2b), j-slice of 16 ----------
    float r2v[16];
    {
        float acc[16];
        const float* b = b2b + sub * 16;
        #pragma unroll
        for (int j = 0; j < 16; ++j) acc[j] = b[j];
        const unsigned* hb2 = &ldsB[node * X2SU];
        const unsigned* w2bP = wp + W2B_OFF + sub * 16;
        #pragma unroll 2
        for (int k4 = 0; k4 < 16; ++k4) {
            uint2 xu = *reinterpret_cast<const uint2*>(hb2 + 2 * k4);
            dot16(uh(xu.x), uh(xu.y),
                  w2bP + (2 * k4) * 64, w2bP + (2 * k4 + 1) * 64, acc);
        }
        #pragma unroll
        for (int j = 0; j < 16; ++j) r2v[j] = fast_tanh(acc[j]);
    }

    // ---------- Phase 6: row L2 norm + write (normal stores) ----------
    float s = 0.f;
    #pragma unroll
    for (int j = 0; j < 16; ++j) s = fmaf(r1v[j], r1v[j], s);
    #pragma unroll
    for (int j = 0; j < 16; ++j) s = fmaf(r2v[j], r2v[j], s);
    ldsS[node * 4 + sub] = s;
    __syncthreads();                     // B6
    float4 sv = reinterpret_cast<const float4*>(ldsS)[node];
    float rn = rsqrtf(sv.x + sv.y + sv.z + sv.w);

    float* orow = out + (size_t)(n0 + node) * 128;
    float4* o1 = reinterpret_cast<float4*>(orow + sub * 16);
    float4* o2 = reinterpret_cast<float4*>(orow + 64 + sub * 16);
    #pragma unroll
    for (int j4 = 0; j4 < 4; ++j4) {
        o1[j4] = make_float4(r1v[j4*4+0]*rn, r1v[j4*4+1]*rn, r1v[j4*4+2]*rn, r1v[j4*4+3]*rn);
        o2[j4] = make_float4(r2v[j4*4+0]*rn, r2v[j4*4+1]*rn, r2v[j4*4+2]*rn, r2v[j4*4+3]*rn);
    }
}

extern "C" void kernel_launch(void* const* d_in, const int* in_sizes, int n_in,
                              void* d_out, int out_size, void* d_ws, size_t ws_size,
                              hipStream_t stream) {
    const float* feat = (const float*)d_in[0];
    const float* hid  = (const float*)d_in[1];
    const float* mail = (const float*)d_in[2];
    const float* w1a  = (const float*)d_in[3];
    const float* b1a  = (const float*)d_in[4];
    const float* w1b  = (const float*)d_in[5];
    const float* b1b  = (const float*)d_in[6];
    const float* w2a  = (const float*)d_in[7];
    const float* b2a  = (const float*)d_in[8];
    const float* w2b  = (const float*)d_in[9];
    const float* b2b  = (const float*)d_in[10];
    float* out = (float*)d_out;
    unsigned* wp = (unsigned*)d_ws;          // 13312 u32 = 53KB packed f16 weights

    const int N = in_sizes[0] / 64;          // 200000
    const int blocks = N / NB;               // 3125

    cvt_weights<<<WTOTAL / 256, 256, 0, stream>>>(w1a, w1b, w2a, w2b, wp);
    node_net_kernel<<<blocks, THREADS, 0, stream>>>(
        feat, hid, mail, b1a, b1b, b2a, b2b, wp, out);
}